// Round 6
// baseline (407.172 us; speedup 1.0000x reference)
//
#include <hip/hip_runtime.h>
#include <hip/hip_bf16.h>

#define T_DIM 2048
#define B_DIM 16
#define D_DIM 1024
#define M_DIM (T_DIM * B_DIM)   // 32768 GEMM rows
#define K_DIM D_DIM             // 1024
#define N_DIM (3 * D_DIM)       // 3072 (cand_x | delta | gate)
#define BD (B_DIM * D_DIM)      // 16384 parallel chains
#define CHUNKS 64
#define CLEN (T_DIM / CHUNKS)   // 32
#define NT (K_DIM / 64)         // 16 K-tiles

typedef __attribute__((ext_vector_type(8))) short bf16x8;
typedef __attribute__((ext_vector_type(4))) float f32x4;
typedef __attribute__((ext_vector_type(16))) float f32x16;
typedef __attribute__((ext_vector_type(4))) unsigned short us4;
typedef __attribute__((ext_vector_type(8))) unsigned short us8;

__device__ __forceinline__ unsigned short f2bf(float f) {
    unsigned int u = __builtin_bit_cast(unsigned int, f);
    u += 0x7fffu + ((u >> 16) & 1u);  // RNE
    return (unsigned short)(u >> 16);
}
__device__ __forceinline__ float bf2f(unsigned short s) {
    unsigned int u = ((unsigned int)s) << 16;
    return __builtin_bit_cast(float, u);
}
__device__ __forceinline__ float sigmoid_f(float x) {
    return __builtin_amdgcn_rcpf(1.0f + __expf(-x));
}
__device__ __forceinline__ float tanh_f(float x) {
    float e = __expf(2.0f * x);
    return 1.0f - 2.0f * __builtin_amdgcn_rcpf(e + 1.0f);
}

__device__ __forceinline__ void gload_lds16(const unsigned short* g, unsigned short* l) {
    __builtin_amdgcn_global_load_lds(
        (const __attribute__((address_space(1))) unsigned int*)g,
        (__attribute__((address_space(3))) unsigned int*)l, 16, 0, 0);
}

// swizzled ds_read of one bf16x8 slice from a 128x64 half-slot; ce0 = elem col
__device__ __forceinline__ bf16x8 lds_rd(const unsigned short* lds, int slot, int srow, int ce0) {
    int ce = ((ce0 * 2) ^ ((srow & 7) << 4)) >> 1;   // byte-swizzle -> elem
    return *reinterpret_cast<const bf16x8*>(lds + slot * 8192 + srow * 64 + ce);
}

// ---------------------------------------------------------------------------
// f32 -> bf16 conversion, 8 elems/thread (nt loads keep fp32 out of L3).
// ---------------------------------------------------------------------------
__global__ __launch_bounds__(256)
void conv_bf16(const float* __restrict__ in, unsigned short* __restrict__ outp, int n8)
{
    int i = blockIdx.x * 256 + threadIdx.x;
    if (i >= n8) return;
    const f32x4* p = reinterpret_cast<const f32x4*>(in) + (size_t)i * 2;
    f32x4 v0 = __builtin_nontemporal_load(p);
    f32x4 v1 = __builtin_nontemporal_load(p + 1);
    us8 w;
    w[0] = f2bf(v0[0]); w[1] = f2bf(v0[1]); w[2] = f2bf(v0[2]); w[3] = f2bf(v0[3]);
    w[4] = f2bf(v1[0]); w[5] = f2bf(v1[1]); w[6] = f2bf(v1[2]); w[7] = f2bf(v1[3]);
    *reinterpret_cast<us8*>(outp + (size_t)i * 8) = w;
}

// ---------------------------------------------------------------------------
// Fused projection GEMM — 256x256 tile, BK=64, 8 waves (2Mx4N), 4-phase
// schedule with counted vmcnt(6), T2 swizzle, setprio, 32x32x16 MFMA,
// LDS-staged nontemporal epilogue.
// ---------------------------------------------------------------------------
__global__ __launch_bounds__(512, 2)
void gemm_fused(const unsigned short* __restrict__ xb,
                const unsigned short* __restrict__ Wb,
                const float* __restrict__ bx, const float* __restrict__ bdl,
                const float* __restrict__ bg,
                unsigned short* __restrict__ cxw, unsigned short* __restrict__ dw,
                unsigned short* __restrict__ gw)
{
    // 128 KiB LDS: K-loop = 4 half-slots x 16KB per operand; epilogue = C-tile
    __shared__ unsigned short lds[8 * 8192];
    unsigned short* ldsA = lds;
    unsigned short* ldsB = lds + 4 * 8192;

    const int NWG = (M_DIM / 256) * (N_DIM / 256);   // 1536, %8 == 0
    int bid = blockIdx.x;
    int wg  = (bid & 7) * (NWG / 8) + (bid >> 3);    // XCD-bijective
    const int bidM = wg / 12;                        // M-outer per XCD
    const int bidN = wg % 12;                        // N inner: x-panel L2-resident
    const int tM  = bidM * 256;
    const int tN  = bidN * 256;
    const int arr = tN >> 10;
    const int nb  = tN & 1023;

    const float* bias = (arr == 0) ? bx : (arr == 1) ? bdl : bg;
    unsigned short* outp = (arr == 0) ? cxw : (arr == 1) ? dw : gw;

    const int tid  = threadIdx.x;
    const int lane = tid & 63;
    const int wid  = tid >> 6;
    const int wr = wid >> 2, wc = wid & 3;           // wave -> 128x64 output
    const int lr   = lane & 15;
    const int la   = lane & 31;
    const int lahi = (lane >> 4) & 1;
    const int khi8 = ((lane >> 5) & 1) * 8;          // k-elem offset within K-step

    const unsigned short* Asrc = xb + (size_t)tM * K_DIM;
    const unsigned short* Bsrc = Wb + (size_t)arr * (D_DIM * K_DIM) + (size_t)nb * K_DIM;

    // staging source geometry (T2 inverse swizzle on the global address)
    const int t8 = tid >> 3;                              // 0..63
    const int ke = (((tid & 7) ^ (t8 & 7)) << 3);         // k-elem offset
    auto arow = [&](int h, int w) {
        int s = w * 64 + t8;
        return ((s >> 4) & 1) * 128 + (h * 4 + (s >> 5)) * 16 + (s & 15);
    };
    const int rA00 = arow(0, 0), rA01 = arow(0, 1);
    const int rA10 = arow(1, 0), rA11 = arow(1, 1);

    auto stA = [&](int t, int r0, int r1, int slot) {
        gload_lds16(Asrc + (size_t)r0 * K_DIM + t * 64 + ke, ldsA + slot * 8192 + wid * 512);
        gload_lds16(Asrc + (size_t)r1 * K_DIM + t * 64 + ke, ldsA + slot * 8192 + 4096 + wid * 512);
    };
    auto stB = [&](int t, int h, int slot) {
        gload_lds16(Bsrc + (size_t)(h * 128 + t8) * K_DIM + t * 64 + ke,      ldsB + slot * 8192 + wid * 512);
        gload_lds16(Bsrc + (size_t)(h * 128 + 64 + t8) * K_DIM + t * 64 + ke, ldsB + slot * 8192 + 4096 + wid * 512);
    };

    f32x16 acc[4][2];
#pragma unroll
    for (int mi = 0; mi < 4; mi++)
#pragma unroll
        for (int ni = 0; ni < 2; ni++)
            acc[mi][ni] = (f32x16)(0.f);

    // Prologue: tile0 (4 halves) + tile1 {B0, A0, B1}  => 14 loads/wave
    stA(0, rA00, rA01, 0);
    stA(0, rA10, rA11, 1);
    stB(0, 0, 0);
    stB(0, 1, 1);
    stB(1, 0, 2);
    stA(1, rA00, rA01, 2);
    stB(1, 1, 3);
    asm volatile("s_waitcnt vmcnt(6)" ::: "memory");   // tile0 arrived; 3 halves in flight
    __builtin_amdgcn_s_barrier();

    bf16x8 bf[2][4], af[4];

    // A fragment row within half-slot for 32x32 fragment mi (half = mi>>1)
#define AROW32(MI) ((2 * ((MI) & 1) + lahi) * 32 + wr * 16 + lr)

#define LOAD_AF32(MI, ASLOT)                                                       \
    do {                                                                           \
        _Pragma("unroll") for (int ks = 0; ks < 4; ks++)                           \
            af[ks] = lds_rd(ldsA, (ASLOT), AROW32(MI), ks * 16 + khi8);            \
    } while (0)

#define PHASE_MFMA32(MI)                                                           \
    do {                                                                           \
        __builtin_amdgcn_s_setprio(1);                                             \
        _Pragma("unroll") for (int ni = 0; ni < 2; ni++)                           \
            _Pragma("unroll") for (int ks = 0; ks < 4; ks++)                       \
                acc[MI][ni] = __builtin_amdgcn_mfma_f32_32x32x16_bf16(             \
                    af[ks], bf[ni][ks], acc[MI][ni], 0, 0, 0);                     \
        __builtin_amdgcn_s_setprio(0);                                             \
    } while (0)

#define WAIT_LGKM()                                          \
    do {                                                     \
        asm volatile("s_waitcnt lgkmcnt(0)" ::: "memory");   \
        __builtin_amdgcn_sched_barrier(0);                   \
    } while (0)

    for (int kt = 0; kt < NT; ++kt) {
        const int par = kt & 1;
        const int a0 = 2 * par, a1 = 2 * par + 1;
        const int bslot = 2 * par + (wc >> 1);
        const int brow  = (wc & 1) * 64;

        // ---- phase 1: all B frags (8 reads) + A mi0 (4 reads); stage A1(kt+1)
#pragma unroll
        for (int ni = 0; ni < 2; ni++)
#pragma unroll
            for (int ks = 0; ks < 4; ks++)
                bf[ni][ks] = lds_rd(ldsB, bslot, brow + ni * 32 + la, ks * 16 + khi8);
        LOAD_AF32(0, a0);
        if (kt + 1 < NT) stA(kt + 1, rA10, rA11, 2 * (1 - par) + 1);
        __builtin_amdgcn_s_barrier();
        WAIT_LGKM();
        PHASE_MFMA32(0);
        __builtin_amdgcn_s_barrier();

        // ---- phase 2: A mi1; stage B0(kt+2) into freed B slot
        LOAD_AF32(1, a0);
        if (kt + 2 < NT) stB(kt + 2, 0, 2 * par);
        __builtin_amdgcn_s_barrier();
        WAIT_LGKM();
        PHASE_MFMA32(1);
        __builtin_amdgcn_s_barrier();

        // ---- phase 3: A mi2 (half1); stage A0(kt+2) into freed A0 slot
        LOAD_AF32(2, a1);
        if (kt + 2 < NT) stA(kt + 2, rA00, rA01, 2 * par);
        __builtin_amdgcn_s_barrier();
        WAIT_LGKM();
        PHASE_MFMA32(2);
        __builtin_amdgcn_s_barrier();

        // ---- phase 4: A mi3; stage B1(kt+2); end-of-tile counted vmcnt
        LOAD_AF32(3, a1);
        if (kt + 2 < NT) stB(kt + 2, 1, 2 * par + 1);
        if (kt < NT - 2) asm volatile("s_waitcnt vmcnt(6)" ::: "memory");
        else             asm volatile("s_waitcnt vmcnt(0)" ::: "memory");
        __builtin_amdgcn_s_barrier();
        WAIT_LGKM();
        PHASE_MFMA32(3);
        __builtin_amdgcn_s_barrier();
    }

    // ---- Epilogue: bias + activation -> bf16 C-tile in LDS (bank-swizzled),
    //      then fully-coalesced nontemporal 16B global stores.
    // 32x32 C/D layout: col = lane&31, row = (reg&3) + 8*(reg>>2) + 4*(lane>>5)
#pragma unroll
    for (int ni = 0; ni < 2; ni++) {
        int lc = wc * 64 + ni * 32 + la;        // local col 0..255
        float bia = bias[nb + lc];
#pragma unroll
        for (int mi = 0; mi < 4; mi++) {
#pragma unroll
            for (int r = 0; r < 16; r++) {
                float v = acc[mi][ni][r] + bia;
                if (arr == 1)      v = sigmoid_f(v);
                else if (arr == 2) v = v * sigmoid_f(v);
                int row  = wr * 128 + mi * 32 + (r & 3) + 8 * (r >> 2) + ((lane >> 5) << 2);
                int byte = (row * 512 + lc * 2) ^ ((row & 7) << 4);
                *reinterpret_cast<unsigned short*>(
                    reinterpret_cast<char*>(lds) + byte) = f2bf(v);
            }
        }
    }
    __syncthreads();
#pragma unroll
    for (int it = 0; it < 16; ++it) {
        int off8 = it * 512 + tid;              // 16B-chunk id, 8192 total
        int row  = off8 >> 5;                   // 32 chunks per 256-col row
        int col8 = (off8 & 31) << 3;
        int byte = (row * 512 + col8 * 2) ^ ((row & 7) << 4);
        us8 v = *reinterpret_cast<const us8*>(reinterpret_cast<char*>(lds) + byte);
        __builtin_nontemporal_store(v,
            reinterpret_cast<us8*>(outp + (size_t)(tM + row) * D_DIM + nb + col8));
    }
#undef AROW32
#undef LOAD_AF32
#undef PHASE_MFMA32
#undef WAIT_LGKM
}

// ---------------------------------------------------------------------------
// Scan pass 1: per (chunk, channel-quad): A = prod(1-d), B = local scan from 0
// ---------------------------------------------------------------------------
__global__ __launch_bounds__(256)
void scan_pass1(const unsigned short* __restrict__ dw,
                const unsigned short* __restrict__ cxw,
                float* __restrict__ Aw, float* __restrict__ Bw)
{
    int g  = blockIdx.x * 256 + threadIdx.x;
    int c  = g / (BD / 4);
    int i0 = (g % (BD / 4)) * 4;
    size_t base = (size_t)c * CLEN * BD + i0;

    float a[4]  = {1.f, 1.f, 1.f, 1.f};
    float hb[4] = {0.f, 0.f, 0.f, 0.f};
    for (int t = 0; t < CLEN; t++) {
        us4 dv = *reinterpret_cast<const us4*>(dw  + base + (size_t)t * BD);
        us4 cv = *reinterpret_cast<const us4*>(cxw + base + (size_t)t * BD);
#pragma unroll
        for (int j = 0; j < 4; j++) {
            float d = bf2f(dv[j]);
            float om = 1.f - d;
            float cand = tanh_f(bf2f(cv[j]));
            hb[j] = om * hb[j] + d * cand;
            a[j] *= om;
        }
    }
    f32x4 av = {a[0], a[1], a[2], a[3]};
    f32x4 bv = {hb[0], hb[1], hb[2], hb[3]};
    *reinterpret_cast<f32x4*>(Aw + (size_t)c * BD + i0) = av;
    *reinterpret_cast<f32x4*>(Bw + (size_t)c * BD + i0) = bv;
}

// ---------------------------------------------------------------------------
// Scan pass 2: sequential combine over chunks (tiny). Writes h[0].
// ---------------------------------------------------------------------------
__global__ __launch_bounds__(256)
void scan_pass2(const float* __restrict__ Aw, const float* __restrict__ Bw,
                const float* __restrict__ h0, float* __restrict__ hin,
                float* __restrict__ hseq)
{
    int i0 = (blockIdx.x * 256 + threadIdx.x) * 4;
    if (i0 >= BD) return;
    f32x4 h = *reinterpret_cast<const f32x4*>(h0 + i0);
    *reinterpret_cast<f32x4*>(hseq + i0) = h;
    for (int c = 0; c < CHUNKS; c++) {
        *reinterpret_cast<f32x4*>(hin + (size_t)c * BD + i0) = h;
        f32x4 A  = *reinterpret_cast<const f32x4*>(Aw + (size_t)c * BD + i0);
        f32x4 Bv = *reinterpret_cast<const f32x4*>(Bw + (size_t)c * BD + i0);
        h = A * h + Bv;
    }
}

// ---------------------------------------------------------------------------
// Scan pass 3: replay each chunk with true h_in; nt-store out and h.
// ---------------------------------------------------------------------------
__global__ __launch_bounds__(256)
void scan_pass3(const unsigned short* __restrict__ dw,
                const unsigned short* __restrict__ cxw,
                const unsigned short* __restrict__ gw,
                const float* __restrict__ hin,
                float* __restrict__ out, float* __restrict__ hseq)
{
    int g  = blockIdx.x * 256 + threadIdx.x;
    int c  = g / (BD / 4);
    int i0 = (g % (BD / 4)) * 4;
    size_t base = (size_t)c * CLEN * BD + i0;

    f32x4 h4 = *reinterpret_cast<const f32x4*>(hin + (size_t)c * BD + i0);
    float h[4] = {h4[0], h4[1], h4[2], h4[3]};
    for (int t = 0; t < CLEN; t++) {
        size_t idx = base + (size_t)t * BD;
        us4 dv = *reinterpret_cast<const us4*>(dw  + idx);
        us4 cv = *reinterpret_cast<const us4*>(cxw + idx);
        us4 gv = *reinterpret_cast<const us4*>(gw  + idx);
        f32x4 o, hv;
#pragma unroll
        for (int j = 0; j < 4; j++) {
            float d = bf2f(dv[j]);
            float om = 1.f - d;
            float cand = tanh_f(bf2f(cv[j]));
            h[j] = om * h[j] + d * cand;
            o[j] = h[j] * bf2f(gv[j]);
            hv[j] = h[j];
        }
        __builtin_nontemporal_store(o,  reinterpret_cast<f32x4*>(out + idx));
        __builtin_nontemporal_store(hv, reinterpret_cast<f32x4*>(hseq + idx + BD));
    }
}

// ---------------------------------------------------------------------------
// Fixup for channels with r_h != 0 (r_h == 0 here -> immediate exit).
// ---------------------------------------------------------------------------
__global__ __launch_bounds__(256)
void scan_fixup(const float* __restrict__ rh, const float* __restrict__ h0,
                const unsigned short* __restrict__ dw,
                const unsigned short* __restrict__ cxw,
                const unsigned short* __restrict__ gw,
                float* __restrict__ out, float* __restrict__ hseq)
{
    int i = blockIdx.x * 256 + threadIdx.x;
    if (i >= BD) return;
    float r = rh[i & (D_DIM - 1)];
    if (r == 0.0f) return;
    float h = h0[i];
    for (int t = 0; t < T_DIM; t++) {
        size_t idx = (size_t)t * BD + i;
        float d = bf2f(dw[idx]);
        float cand = tanh_f(bf2f(cxw[idx]) + r * h);
        h = (1.f - d) * h + d * cand;
        out[idx] = h * bf2f(gw[idx]);
        hseq[idx + BD] = h;
    }
}

extern "C" void kernel_launch(void* const* d_in, const int* in_sizes, int n_in,
                              void* d_out, int out_size, void* d_ws, size_t ws_size,
                              hipStream_t stream)
{
    const float* x   = (const float*)d_in[0];
    const float* h0  = (const float*)d_in[1];
    const float* Wx  = (const float*)d_in[2];
    const float* rh  = (const float*)d_in[3];
    const float* Wd  = (const float*)d_in[4];
    const float* Wg  = (const float*)d_in[5];
    const float* bx  = (const float*)d_in[6];
    const float* bdl = (const float*)d_in[7];
    const float* bg  = (const float*)d_in[8];

    float* out  = (float*)d_out;                       // [T,B,D]
    float* hseq = out + (size_t)T_DIM * BD;            // [T+1,B,D]

    unsigned short* dw  = (unsigned short*)d_ws;
    unsigned short* cxw = dw  + (size_t)M_DIM * D_DIM;
    unsigned short* gw  = cxw + (size_t)M_DIM * D_DIM;
    float* Aw  = (float*)(gw + (size_t)M_DIM * D_DIM);
    float* Bw  = Aw + (size_t)CHUNKS * BD;
    float* hin = Bw + (size_t)CHUNKS * BD;

    // bf16 x and W live in the not-yet-written `out` region (GEMM finishes
    // before scan_pass3 writes out). 67.1 MB + 6.3 MB < 134 MB.
    unsigned short* xb = (unsigned short*)d_out;
    unsigned short* Wb = xb + (size_t)M_DIM * K_DIM;

    conv_bf16<<<dim3(M_DIM * K_DIM / 8 / 256), dim3(256), 0, stream>>>(x, xb, M_DIM * K_DIM / 8);
    conv_bf16<<<dim3(D_DIM * K_DIM / 8 / 256), dim3(256), 0, stream>>>(Wx, Wb, D_DIM * K_DIM / 8);
    conv_bf16<<<dim3(D_DIM * K_DIM / 8 / 256), dim3(256), 0, stream>>>(Wd, Wb + (size_t)D_DIM * K_DIM, D_DIM * K_DIM / 8);
    conv_bf16<<<dim3(D_DIM * K_DIM / 8 / 256), dim3(256), 0, stream>>>(Wg, Wb + (size_t)2 * D_DIM * K_DIM, D_DIM * K_DIM / 8);

    gemm_fused<<<dim3((M_DIM / 256) * (N_DIM / 256)), dim3(512), 0, stream>>>(
        xb, Wb, bx, bdl, bg, cxw, dw, gw);

    scan_pass1<<<dim3(CHUNKS * BD / 4 / 256), dim3(256), 0, stream>>>(dw, cxw, Aw, Bw);
    scan_pass2<<<dim3(BD / 4 / 256 + 1), dim3(256), 0, stream>>>(Aw, Bw, h0, hin, hseq);
    scan_pass3<<<dim3(CHUNKS * BD / 4 / 256), dim3(256), 0, stream>>>(dw, cxw, gw, hin, out, hseq);
    scan_fixup<<<dim3(BD / 256), dim3(256), 0, stream>>>(rh, h0, dw, cxw, gw, out, hseq);
}

// Round 7
// 375.378 us; speedup vs baseline: 1.0847x; 1.0847x over previous
//
#include <hip/hip_runtime.h>
#include <hip/hip_bf16.h>

#define T_DIM 2048
#define B_DIM 16
#define D_DIM 1024
#define M_DIM (T_DIM * B_DIM)   // 32768 GEMM rows
#define K_DIM D_DIM             // 1024
#define N_DIM (3 * D_DIM)       // 3072 (cand_x | delta | gate)
#define BD (B_DIM * D_DIM)      // 16384 parallel chains
#define CHUNKS 64
#define CLEN (T_DIM / CHUNKS)   // 32
#define NT (K_DIM / 64)         // 16 K-tiles

typedef __attribute__((ext_vector_type(8))) short bf16x8;
typedef __attribute__((ext_vector_type(4))) float f32x4;
typedef __attribute__((ext_vector_type(4))) unsigned short us4;
typedef __attribute__((ext_vector_type(8))) unsigned short us8;

__device__ __forceinline__ unsigned short f2bf(float f) {
    unsigned int u = __builtin_bit_cast(unsigned int, f);
    u += 0x7fffu + ((u >> 16) & 1u);  // RNE
    return (unsigned short)(u >> 16);
}
__device__ __forceinline__ float bf2f(unsigned short s) {
    unsigned int u = ((unsigned int)s) << 16;
    return __builtin_bit_cast(float, u);
}
__device__ __forceinline__ float sigmoid_f(float x) {
    return __builtin_amdgcn_rcpf(1.0f + __expf(-x));
}
__device__ __forceinline__ float tanh_f(float x) {
    float e = __expf(2.0f * x);
    return 1.0f - 2.0f * __builtin_amdgcn_rcpf(e + 1.0f);
}

__device__ __forceinline__ void gload_lds16(const unsigned short* g, unsigned short* l) {
    __builtin_amdgcn_global_load_lds(
        (const __attribute__((address_space(1))) unsigned int*)g,
        (__attribute__((address_space(3))) unsigned int*)l, 16, 0, 0);
}

// swizzled ds_read of one bf16x8 fragment slice from a 128x64 half-slot
__device__ __forceinline__ bf16x8 lds_rd(const unsigned short* lds, int slot, int srow, int kk, int lk) {
    int ce = (((kk * 64) + (lk * 16)) ^ ((srow & 7) << 4)) >> 1;   // byte-swizzle -> elem
    return *reinterpret_cast<const bf16x8*>(lds + slot * 8192 + srow * 64 + ce);
}

// ---------------------------------------------------------------------------
// Single merged f32 -> bf16 conversion for x, Wx, Wd, Wg (1 launch).
// 8 elems/thread; block-aligned region boundaries (all sizes % 2048 == 0).
// ---------------------------------------------------------------------------
#define XN8 (M_DIM * K_DIM / 8)
#define WN8 (D_DIM * K_DIM / 8)
__global__ __launch_bounds__(256)
void conv_all(const float* __restrict__ x,  const float* __restrict__ Wx,
              const float* __restrict__ Wd, const float* __restrict__ Wg,
              unsigned short* __restrict__ xb, unsigned short* __restrict__ Wb)
{
    int i = blockIdx.x * 256 + threadIdx.x;
    const float* src;
    unsigned short* dst;
    int off;
    if (i < XN8)                { src = x;  dst = xb;               off = i; }
    else if (i < XN8 + WN8)     { src = Wx; dst = Wb;               off = i - XN8; }
    else if (i < XN8 + 2 * WN8) { src = Wd; dst = Wb + (size_t)WN8 * 8;     off = i - XN8 - WN8; }
    else                        { src = Wg; dst = Wb + (size_t)2 * WN8 * 8; off = i - XN8 - 2 * WN8; }
    const f32x4* p = reinterpret_cast<const f32x4*>(src) + (size_t)off * 2;
    f32x4 v0 = __builtin_nontemporal_load(p);
    f32x4 v1 = __builtin_nontemporal_load(p + 1);
    us8 w;
    w[0] = f2bf(v0[0]); w[1] = f2bf(v0[1]); w[2] = f2bf(v0[2]); w[3] = f2bf(v0[3]);
    w[4] = f2bf(v1[0]); w[5] = f2bf(v1[1]); w[6] = f2bf(v1[2]); w[7] = f2bf(v1[3]);
    *reinterpret_cast<us8*>(dst + (size_t)off * 8) = w;
}

// ---------------------------------------------------------------------------
// Fused projection GEMM — 256x256 tile, BK=64, 8 waves (2Mx4N), 4-phase
// schedule, counted vmcnt(6), T2 swizzle, setprio, 16x16x32 MFMA with
// SWAPPED operands (acc holds C^T quadrants -> packed b64 LDS epilogue).
// ---------------------------------------------------------------------------
__global__ __launch_bounds__(512, 2)
void gemm_fused(const unsigned short* __restrict__ xb,
                const unsigned short* __restrict__ Wb,
                const float* __restrict__ bx, const float* __restrict__ bdl,
                const float* __restrict__ bg,
                unsigned short* __restrict__ cxw, unsigned short* __restrict__ dw,
                unsigned short* __restrict__ gw)
{
    // 128 KiB LDS: K-loop = 4 half-slots x 16KB per operand; epilogue = C-tile
    __shared__ unsigned short lds[8 * 8192];
    unsigned short* ldsA = lds;
    unsigned short* ldsB = lds + 4 * 8192;

    const int NWG = (M_DIM / 256) * (N_DIM / 256);   // 1536, %8 == 0
    int bid = blockIdx.x;
    int wg  = (bid & 7) * (NWG / 8) + (bid >> 3);    // XCD-bijective
    const int bidM = wg / 12;                        // M-outer per XCD
    const int bidN = wg % 12;                        // N inner: x-panel L2-resident
    const int tM  = bidM * 256;
    const int tN  = bidN * 256;
    const int arr = tN >> 10;
    const int nb  = tN & 1023;

    const float* bias = (arr == 0) ? bx : (arr == 1) ? bdl : bg;
    unsigned short* outp = (arr == 0) ? cxw : (arr == 1) ? dw : gw;

    const int tid  = threadIdx.x;
    const int lane = tid & 63;
    const int wid  = tid >> 6;
    const int wr = wid >> 2, wc = wid & 3;           // wave -> 128x64 output
    const int lr = lane & 15, lk = lane >> 4;

    const unsigned short* Asrc = xb + (size_t)tM * K_DIM;
    const unsigned short* Bsrc = Wb + (size_t)arr * (D_DIM * K_DIM) + (size_t)nb * K_DIM;

    // staging source geometry (T2 inverse swizzle on the global address)
    const int t8 = tid >> 3;                              // 0..63
    const int ke = (((tid & 7) ^ (t8 & 7)) << 3);         // k-elem offset
    auto arow = [&](int h, int w) {
        int s = w * 64 + t8;
        return ((s >> 4) & 1) * 128 + (h * 4 + (s >> 5)) * 16 + (s & 15);
    };
    const int rA00 = arow(0, 0), rA01 = arow(0, 1);
    const int rA10 = arow(1, 0), rA11 = arow(1, 1);

    auto stA = [&](int t, int r0, int r1, int slot) {
        gload_lds16(Asrc + (size_t)r0 * K_DIM + t * 64 + ke, ldsA + slot * 8192 + wid * 512);
        gload_lds16(Asrc + (size_t)r1 * K_DIM + t * 64 + ke, ldsA + slot * 8192 + 4096 + wid * 512);
    };
    auto stB = [&](int t, int h, int slot) {
        gload_lds16(Bsrc + (size_t)(h * 128 + t8) * K_DIM + t * 64 + ke,      ldsB + slot * 8192 + wid * 512);
        gload_lds16(Bsrc + (size_t)(h * 128 + 64 + t8) * K_DIM + t * 64 + ke, ldsB + slot * 8192 + 4096 + wid * 512);
    };

    f32x4 acc[8][4];
#pragma unroll
    for (int mi = 0; mi < 8; mi++)
#pragma unroll
        for (int ni = 0; ni < 4; ni++)
            acc[mi][ni] = (f32x4){0.f, 0.f, 0.f, 0.f};

    // Prologue: tile0 (4 halves) + tile1 {B0, A0, B1}  => 14 loads/wave
    stA(0, rA00, rA01, 0);
    stA(0, rA10, rA11, 1);
    stB(0, 0, 0);
    stB(0, 1, 1);
    stB(1, 0, 2);
    stA(1, rA00, rA01, 2);
    stB(1, 1, 3);
    asm volatile("s_waitcnt vmcnt(6)" ::: "memory");   // tile0 arrived; 3 halves in flight
    __builtin_amdgcn_s_barrier();

    bf16x8 bf[4][2], af[2][2];

#define LOAD_AF(P, ASLOT)                                                          \
    do {                                                                           \
        _Pragma("unroll") for (int j = 0; j < 2; j++)                              \
            _Pragma("unroll") for (int kk = 0; kk < 2; kk++)                       \
                af[j][kk] = lds_rd(ldsA, (ASLOT),                                  \
                                   ((2 * (P) + j) & 3) * 32 + wr * 16 + lr, kk, lk); \
    } while (0)

// operand-swapped: acc = bf * af  => acc holds C^T (lane&15 = C-row,
// reg = C-col). A/B fragment lane layouts are identical for 16x16x32.
#define PHASE_MFMA(P)                                                              \
    do {                                                                           \
        __builtin_amdgcn_s_setprio(1);                                             \
        _Pragma("unroll") for (int j = 0; j < 2; j++)                              \
            _Pragma("unroll") for (int ni = 0; ni < 4; ni++) {                     \
                acc[2 * (P) + j][ni] = __builtin_amdgcn_mfma_f32_16x16x32_bf16(    \
                    bf[ni][0], af[j][0], acc[2 * (P) + j][ni], 0, 0, 0);           \
                acc[2 * (P) + j][ni] = __builtin_amdgcn_mfma_f32_16x16x32_bf16(    \
                    bf[ni][1], af[j][1], acc[2 * (P) + j][ni], 0, 0, 0);           \
            }                                                                      \
        __builtin_amdgcn_s_setprio(0);                                             \
    } while (0)

#define WAIT_LGKM()                                          \
    do {                                                     \
        asm volatile("s_waitcnt lgkmcnt(0)" ::: "memory");   \
        __builtin_amdgcn_sched_barrier(0);                   \
    } while (0)

    for (int kt = 0; kt < NT; ++kt) {
        const int par = kt & 1;
        const int a0 = 2 * par, a1 = 2 * par + 1;
        const int bslot = 2 * par + (wc >> 1);
        const int brow  = (wc & 1) * 64;

        // ---- phase 1: all B frags (8 reads) + A mi0-1 (4 reads); stage A1(kt+1)
#pragma unroll
        for (int ni = 0; ni < 4; ni++)
#pragma unroll
            for (int kk = 0; kk < 2; kk++)
                bf[ni][kk] = lds_rd(ldsB, bslot, brow + ni * 16 + lr, kk, lk);
        LOAD_AF(0, a0);
        if (kt + 1 < NT) stA(kt + 1, rA10, rA11, 2 * (1 - par) + 1);
        __builtin_amdgcn_s_barrier();
        WAIT_LGKM();
        PHASE_MFMA(0);
        __builtin_amdgcn_s_barrier();

        // ---- phase 2: A mi2-3; stage B0(kt+2) into freed B slot
        LOAD_AF(1, a0);
        if (kt + 2 < NT) stB(kt + 2, 0, 2 * par);
        __builtin_amdgcn_s_barrier();
        WAIT_LGKM();
        PHASE_MFMA(1);
        __builtin_amdgcn_s_barrier();

        // ---- phase 3: A mi4-5 (half1); stage A0(kt+2) into freed A0 slot
        LOAD_AF(2, a1);
        if (kt + 2 < NT) stA(kt + 2, rA00, rA01, 2 * par);
        __builtin_amdgcn_s_barrier();
        WAIT_LGKM();
        PHASE_MFMA(2);
        __builtin_amdgcn_s_barrier();

        // ---- phase 4: A mi6-7; stage B1(kt+2); end-of-tile counted vmcnt
        LOAD_AF(3, a1);
        if (kt + 2 < NT) stB(kt + 2, 1, 2 * par + 1);
        if (kt < NT - 2) asm volatile("s_waitcnt vmcnt(6)" ::: "memory");
        else             asm volatile("s_waitcnt vmcnt(0)" ::: "memory");
        __builtin_amdgcn_s_barrier();
        WAIT_LGKM();
        PHASE_MFMA(3);
        __builtin_amdgcn_s_barrier();
    }

    // ---- Epilogue: acc = C^T quadrants: lane holds 4 consecutive C-cols at
    //      one C-row -> pack 4 bf16 -> one swizzled ds_write_b64 (32/lane),
    //      then fully-coalesced nontemporal 16B global stores.
#pragma unroll
    for (int mi = 0; mi < 8; mi++) {
        int row = wr * 128 + mi * 16 + lr;        // C-row (local 0..255)
#pragma unroll
        for (int ni = 0; ni < 4; ni++) {
            int col0 = wc * 64 + ni * 16 + lk * 4; // first of 4 consecutive C-cols
            f32x4 bia = *reinterpret_cast<const f32x4*>(bias + nb + col0);
            us4 w;
#pragma unroll
            for (int r = 0; r < 4; r++) {
                float v = acc[mi][ni][r] + bia[r];
                if (arr == 1)      v = sigmoid_f(v);
                else if (arr == 2) v = v * sigmoid_f(v);
                w[r] = f2bf(v);
            }
            int byte = (row * 512 + col0 * 2) ^ ((row & 7) << 4);
            *reinterpret_cast<us4*>(reinterpret_cast<char*>(lds) + byte) = w;
        }
    }
    __syncthreads();
#pragma unroll
    for (int it = 0; it < 16; ++it) {
        int off8 = it * 512 + tid;              // 16B-chunk id, 8192 total
        int row  = off8 >> 5;                   // 32 chunks per 256-col row
        int col8 = (off8 & 31) << 3;
        int byte = (row * 512 + col8 * 2) ^ ((row & 7) << 4);
        us8 v = *reinterpret_cast<const us8*>(reinterpret_cast<char*>(lds) + byte);
        __builtin_nontemporal_store(v,
            reinterpret_cast<us8*>(outp + (size_t)(tM + row) * D_DIM + nb + col8));
    }
#undef LOAD_AF
#undef PHASE_MFMA
#undef WAIT_LGKM
}

// ---------------------------------------------------------------------------
// Scan pass 1: per (chunk, channel-quad): A = prod(1-d), B = local scan from 0
// ---------------------------------------------------------------------------
__global__ __launch_bounds__(256)
void scan_pass1(const unsigned short* __restrict__ dw,
                const unsigned short* __restrict__ cxw,
                float* __restrict__ Aw, float* __restrict__ Bw)
{
    int g  = blockIdx.x * 256 + threadIdx.x;
    int c  = g / (BD / 4);
    int i0 = (g % (BD / 4)) * 4;
    size_t base = (size_t)c * CLEN * BD + i0;

    float a[4]  = {1.f, 1.f, 1.f, 1.f};
    float hb[4] = {0.f, 0.f, 0.f, 0.f};
    for (int t = 0; t < CLEN; t++) {
        us4 dv = *reinterpret_cast<const us4*>(dw  + base + (size_t)t * BD);
        us4 cv = *reinterpret_cast<const us4*>(cxw + base + (size_t)t * BD);
#pragma unroll
        for (int j = 0; j < 4; j++) {
            float d = bf2f(dv[j]);
            float om = 1.f - d;
            float cand = tanh_f(bf2f(cv[j]));
            hb[j] = om * hb[j] + d * cand;
            a[j] *= om;
        }
    }
    f32x4 av = {a[0], a[1], a[2], a[3]};
    f32x4 bv = {hb[0], hb[1], hb[2], hb[3]};
    *reinterpret_cast<f32x4*>(Aw + (size_t)c * BD + i0) = av;
    *reinterpret_cast<f32x4*>(Bw + (size_t)c * BD + i0) = bv;
}

// ---------------------------------------------------------------------------
// Scan pass 2: sequential combine over chunks (tiny). Writes h[0].
// ---------------------------------------------------------------------------
__global__ __launch_bounds__(256)
void scan_pass2(const float* __restrict__ Aw, const float* __restrict__ Bw,
                const float* __restrict__ h0, float* __restrict__ hin,
                float* __restrict__ hseq)
{
    int i0 = (blockIdx.x * 256 + threadIdx.x) * 4;
    if (i0 >= BD) return;
    f32x4 h = *reinterpret_cast<const f32x4*>(h0 + i0);
    *reinterpret_cast<f32x4*>(hseq + i0) = h;
    for (int c = 0; c < CHUNKS; c++) {
        *reinterpret_cast<f32x4*>(hin + (size_t)c * BD + i0) = h;
        f32x4 A  = *reinterpret_cast<const f32x4*>(Aw + (size_t)c * BD + i0);
        f32x4 Bv = *reinterpret_cast<const f32x4*>(Bw + (size_t)c * BD + i0);
        h = A * h + Bv;
    }
}

// ---------------------------------------------------------------------------
// Scan pass 3: replay each chunk with true h_in; nt-store out and h.
// ---------------------------------------------------------------------------
__global__ __launch_bounds__(256)
void scan_pass3(const unsigned short* __restrict__ dw,
                const unsigned short* __restrict__ cxw,
                const unsigned short* __restrict__ gw,
                const float* __restrict__ hin,
                float* __restrict__ out, float* __restrict__ hseq)
{
    int g  = blockIdx.x * 256 + threadIdx.x;
    int c  = g / (BD / 4);
    int i0 = (g % (BD / 4)) * 4;
    size_t base = (size_t)c * CLEN * BD + i0;

    f32x4 h4 = *reinterpret_cast<const f32x4*>(hin + (size_t)c * BD + i0);
    float h[4] = {h4[0], h4[1], h4[2], h4[3]};
    for (int t = 0; t < CLEN; t++) {
        size_t idx = base + (size_t)t * BD;
        us4 dv = *reinterpret_cast<const us4*>(dw  + idx);
        us4 cv = *reinterpret_cast<const us4*>(cxw + idx);
        us4 gv = *reinterpret_cast<const us4*>(gw  + idx);
        f32x4 o, hv;
#pragma unroll
        for (int j = 0; j < 4; j++) {
            float d = bf2f(dv[j]);
            float om = 1.f - d;
            float cand = tanh_f(bf2f(cv[j]));
            h[j] = om * h[j] + d * cand;
            o[j] = h[j] * bf2f(gv[j]);
            hv[j] = h[j];
        }
        __builtin_nontemporal_store(o,  reinterpret_cast<f32x4*>(out + idx));
        __builtin_nontemporal_store(hv, reinterpret_cast<f32x4*>(hseq + idx + BD));
    }
}

// ---------------------------------------------------------------------------
// Fixup for channels with r_h != 0 (r_h == 0 here -> immediate exit).
// ---------------------------------------------------------------------------
__global__ __launch_bounds__(256)
void scan_fixup(const float* __restrict__ rh, const float* __restrict__ h0,
                const unsigned short* __restrict__ dw,
                const unsigned short* __restrict__ cxw,
                const unsigned short* __restrict__ gw,
                float* __restrict__ out, float* __restrict__ hseq)
{
    int i = blockIdx.x * 256 + threadIdx.x;
    if (i >= BD) return;
    float r = rh[i & (D_DIM - 1)];
    if (r == 0.0f) return;
    float h = h0[i];
    for (int t = 0; t < T_DIM; t++) {
        size_t idx = (size_t)t * BD + i;
        float d = bf2f(dw[idx]);
        float cand = tanh_f(bf2f(cxw[idx]) + r * h);
        h = (1.f - d) * h + d * cand;
        out[idx] = h * bf2f(gw[idx]);
        hseq[idx + BD] = h;
    }
}

extern "C" void kernel_launch(void* const* d_in, const int* in_sizes, int n_in,
                              void* d_out, int out_size, void* d_ws, size_t ws_size,
                              hipStream_t stream)
{
    const float* x   = (const float*)d_in[0];
    const float* h0  = (const float*)d_in[1];
    const float* Wx  = (const float*)d_in[2];
    const float* rh  = (const float*)d_in[3];
    const float* Wd  = (const float*)d_in[4];
    const float* Wg  = (const float*)d_in[5];
    const float* bx  = (const float*)d_in[6];
    const float* bdl = (const float*)d_in[7];
    const float* bg  = (const float*)d_in[8];

    float* out  = (float*)d_out;                       // [T,B,D]
    float* hseq = out + (size_t)T_DIM * BD;            // [T+1,B,D]

    unsigned short* dw  = (unsigned short*)d_ws;
    unsigned short* cxw = dw  + (size_t)M_DIM * D_DIM;
    unsigned short* gw  = cxw + (size_t)M_DIM * D_DIM;
    float* Aw  = (float*)(gw + (size_t)M_DIM * D_DIM);
    float* Bw  = Aw + (size_t)CHUNKS * BD;
    float* hin = Bw + (size_t)CHUNKS * BD;

    // bf16 x and W live in the not-yet-written `out` region (GEMM finishes
    // before scan_pass3 writes out). 67.1 MB + 6.3 MB < 134 MB.
    unsigned short* xb = (unsigned short*)d_out;
    unsigned short* Wb = xb + (size_t)M_DIM * K_DIM;

    conv_all<<<dim3((XN8 + 3 * WN8) / 256), dim3(256), 0, stream>>>(x, Wx, Wd, Wg, xb, Wb);

    gemm_fused<<<dim3((M_DIM / 256) * (N_DIM / 256)), dim3(512), 0, stream>>>(
        xb, Wb, bx, bdl, bg, cxw, dw, gw);

    scan_pass1<<<dim3(CHUNKS * BD / 4 / 256), dim3(256), 0, stream>>>(dw, cxw, Aw, Bw);
    scan_pass2<<<dim3(BD / 4 / 256 + 1), dim3(256), 0, stream>>>(Aw, Bw, h0, hin, hseq);
    scan_pass3<<<dim3(CHUNKS * BD / 4 / 256), dim3(256), 0, stream>>>(dw, cxw, gw, hin, out, hseq);
    scan_fixup<<<dim3(BD / 256), dim3(256), 0, stream>>>(rh, h0, dw, cxw, gw, out, hseq);
}

// Round 8
// 371.398 us; speedup vs baseline: 1.0963x; 1.0107x over previous
//
#include <hip/hip_runtime.h>
#include <hip/hip_bf16.h>

#define T_DIM 2048
#define B_DIM 16
#define D_DIM 1024
#define M_DIM (T_DIM * B_DIM)   // 32768 GEMM rows
#define K_DIM D_DIM             // 1024
#define N_DIM (3 * D_DIM)       // 3072 (cand_x | delta | gate)
#define BD (B_DIM * D_DIM)      // 16384 parallel chains
#define CHUNKS 64
#define CLEN (T_DIM / CHUNKS)   // 32
#define NT (K_DIM / 64)         // 16 K-tiles

typedef __attribute__((ext_vector_type(8))) short bf16x8;
typedef __attribute__((ext_vector_type(4))) float f32x4;
typedef __attribute__((ext_vector_type(4))) unsigned short us4;
typedef __attribute__((ext_vector_type(8))) unsigned short us8;

__device__ __forceinline__ unsigned short f2bf(float f) {
    unsigned int u = __builtin_bit_cast(unsigned int, f);
    u += 0x7fffu + ((u >> 16) & 1u);  // RNE
    return (unsigned short)(u >> 16);
}
__device__ __forceinline__ float bf2f(unsigned short s) {
    unsigned int u = ((unsigned int)s) << 16;
    return __builtin_bit_cast(float, u);
}
__device__ __forceinline__ float sigmoid_f(float x) {
    return __builtin_amdgcn_rcpf(1.0f + __expf(-x));
}
__device__ __forceinline__ float tanh_f(float x) {
    float e = __expf(2.0f * x);
    return 1.0f - 2.0f * __builtin_amdgcn_rcpf(e + 1.0f);
}

__device__ __forceinline__ void gload_lds16(const unsigned short* g, unsigned short* l) {
    __builtin_amdgcn_global_load_lds(
        (const __attribute__((address_space(1))) unsigned int*)g,
        (__attribute__((address_space(3))) unsigned int*)l, 16, 0, 0);
}

// swizzled ds_read of one bf16x8 fragment slice from a 128x64 half-slot
__device__ __forceinline__ bf16x8 lds_rd(const unsigned short* lds, int slot, int srow, int kk, int lk) {
    int ce = (((kk * 64) + (lk * 16)) ^ ((srow & 7) << 4)) >> 1;   // byte-swizzle -> elem
    return *reinterpret_cast<const bf16x8*>(lds + slot * 8192 + srow * 64 + ce);
}

// ---------------------------------------------------------------------------
// Single merged f32 -> bf16 conversion for x, Wx, Wd, Wg (1 launch).
// ---------------------------------------------------------------------------
#define XN8 (M_DIM * K_DIM / 8)
#define WN8 (D_DIM * K_DIM / 8)
__global__ __launch_bounds__(256)
void conv_all(const float* __restrict__ x,  const float* __restrict__ Wx,
              const float* __restrict__ Wd, const float* __restrict__ Wg,
              unsigned short* __restrict__ xb, unsigned short* __restrict__ Wb)
{
    int i = blockIdx.x * 256 + threadIdx.x;
    const float* src;
    unsigned short* dst;
    int off;
    if (i < XN8)                { src = x;  dst = xb;               off = i; }
    else if (i < XN8 + WN8)     { src = Wx; dst = Wb;               off = i - XN8; }
    else if (i < XN8 + 2 * WN8) { src = Wd; dst = Wb + (size_t)WN8 * 8;     off = i - XN8 - WN8; }
    else                        { src = Wg; dst = Wb + (size_t)2 * WN8 * 8; off = i - XN8 - 2 * WN8; }
    const f32x4* p = reinterpret_cast<const f32x4*>(src) + (size_t)off * 2;
    f32x4 v0 = __builtin_nontemporal_load(p);
    f32x4 v1 = __builtin_nontemporal_load(p + 1);
    us8 w;
    w[0] = f2bf(v0[0]); w[1] = f2bf(v0[1]); w[2] = f2bf(v0[2]); w[3] = f2bf(v0[3]);
    w[4] = f2bf(v1[0]); w[5] = f2bf(v1[1]); w[6] = f2bf(v1[2]); w[7] = f2bf(v1[3]);
    *reinterpret_cast<us8*>(dst + (size_t)off * 8) = w;
}

// ---------------------------------------------------------------------------
// Fused projection GEMM — 256x256 tile, BK=64, 8 waves (2Mx4N), 4 phases,
// register-pipelined fragment loads (afP/afQ ping-pong, bf prefetch at ph3),
// counted vmcnt(6), T2 swizzle, setprio, swapped-operand MFMA, LDS epilogue.
// ---------------------------------------------------------------------------
__global__ __launch_bounds__(512, 2)
void gemm_fused(const unsigned short* __restrict__ xb,
                const unsigned short* __restrict__ Wb,
                const float* __restrict__ bx, const float* __restrict__ bdl,
                const float* __restrict__ bg,
                unsigned short* __restrict__ cxw, unsigned short* __restrict__ dw,
                unsigned short* __restrict__ gw)
{
    // 128 KiB LDS: K-loop = 4 half-slots x 16KB per operand; epilogue = C-tile
    __shared__ unsigned short lds[8 * 8192];
    unsigned short* ldsA = lds;
    unsigned short* ldsB = lds + 4 * 8192;

    const int NWG = (M_DIM / 256) * (N_DIM / 256);   // 1536, %8 == 0
    int bid = blockIdx.x;
    int wg  = (bid & 7) * (NWG / 8) + (bid >> 3);    // XCD-bijective
    const int bidM = wg / 12;                        // M-outer per XCD
    const int bidN = wg % 12;                        // N inner: x-panel L2-resident
    const int tM  = bidM * 256;
    const int tN  = bidN * 256;
    const int arr = tN >> 10;
    const int nb  = tN & 1023;

    const float* bias = (arr == 0) ? bx : (arr == 1) ? bdl : bg;
    unsigned short* outp = (arr == 0) ? cxw : (arr == 1) ? dw : gw;

    const int tid  = threadIdx.x;
    const int lane = tid & 63;
    const int wid  = tid >> 6;
    const int wr = wid >> 2, wc = wid & 3;           // wave -> 128x64 output
    const int lr = lane & 15, lk = lane >> 4;

    const unsigned short* Asrc = xb + (size_t)tM * K_DIM;
    const unsigned short* Bsrc = Wb + (size_t)arr * (D_DIM * K_DIM) + (size_t)nb * K_DIM;

    // staging source geometry (T2 inverse swizzle on the global address)
    const int t8 = tid >> 3;                              // 0..63
    const int ke = (((tid & 7) ^ (t8 & 7)) << 3);         // k-elem offset
    auto arow = [&](int h, int w) {
        int s = w * 64 + t8;
        return ((s >> 4) & 1) * 128 + (h * 4 + (s >> 5)) * 16 + (s & 15);
    };
    const int rA00 = arow(0, 0), rA01 = arow(0, 1);
    const int rA10 = arow(1, 0), rA11 = arow(1, 1);

    auto stA = [&](int t, int r0, int r1, int slot) {
        gload_lds16(Asrc + (size_t)r0 * K_DIM + t * 64 + ke, ldsA + slot * 8192 + wid * 512);
        gload_lds16(Asrc + (size_t)r1 * K_DIM + t * 64 + ke, ldsA + slot * 8192 + 4096 + wid * 512);
    };
    auto stB = [&](int t, int h, int slot) {
        gload_lds16(Bsrc + (size_t)(h * 128 + t8) * K_DIM + t * 64 + ke,      ldsB + slot * 8192 + wid * 512);
        gload_lds16(Bsrc + (size_t)(h * 128 + 64 + t8) * K_DIM + t * 64 + ke, ldsB + slot * 8192 + 4096 + wid * 512);
    };

    f32x4 acc[8][4];
#pragma unroll
    for (int mi = 0; mi < 8; mi++)
#pragma unroll
        for (int ni = 0; ni < 4; ni++)
            acc[mi][ni] = (f32x4){0.f, 0.f, 0.f, 0.f};

    // Prologue: tile0 (4 halves) + tile1 {B0, A0, B1}  => 14 loads/wave
    stA(0, rA00, rA01, 0);
    stA(0, rA10, rA11, 1);
    stB(0, 0, 0);
    stB(0, 1, 1);
    stB(1, 0, 2);
    stA(1, rA00, rA01, 2);
    stB(1, 1, 3);
    asm volatile("s_waitcnt vmcnt(6)" ::: "memory");   // tile0 arrived; 6 in flight
    __builtin_amdgcn_s_barrier();

    const int brow = (wc & 1) * 64;
    bf16x8 bf[4][2], afP[2][2], afQ[2][2];

#define RD_AF(DST, P, ASLOT)                                                       \
    do {                                                                           \
        _Pragma("unroll") for (int j = 0; j < 2; j++)                              \
            _Pragma("unroll") for (int kk = 0; kk < 2; kk++)                       \
                DST[j][kk] = lds_rd(ldsA, (ASLOT),                                 \
                                    ((2 * (P) + j) & 3) * 32 + wr * 16 + lr, kk, lk); \
    } while (0)

#define RD_BF(BSLOT)                                                               \
    do {                                                                           \
        _Pragma("unroll") for (int ni = 0; ni < 4; ni++)                           \
            _Pragma("unroll") for (int kk = 0; kk < 2; kk++)                       \
                bf[ni][kk] = lds_rd(ldsB, (BSLOT), brow + ni * 16 + lr, kk, lk);   \
    } while (0)

// operand-swapped: acc = bf * af  => acc holds C^T quadrants.
#define MFMA8(P, AF)                                                               \
    do {                                                                           \
        __builtin_amdgcn_s_setprio(1);                                             \
        _Pragma("unroll") for (int j = 0; j < 2; j++)                              \
            _Pragma("unroll") for (int ni = 0; ni < 4; ni++) {                     \
                acc[2 * (P) + j][ni] = __builtin_amdgcn_mfma_f32_16x16x32_bf16(    \
                    bf[ni][0], AF[j][0], acc[2 * (P) + j][ni], 0, 0, 0);           \
                acc[2 * (P) + j][ni] = __builtin_amdgcn_mfma_f32_16x16x32_bf16(    \
                    bf[ni][1], AF[j][1], acc[2 * (P) + j][ni], 0, 0, 0);           \
            }                                                                      \
        __builtin_amdgcn_s_setprio(0);                                             \
    } while (0)

// One K-tile: frag reads are pipelined one phase ahead (afP/afQ ping-pong);
// staging schedule and vmcnt points identical to the verified r7 kernel.
#define TILE(KT, PAR, LAST)                                                        \
    do {                                                                           \
        const int a0s = 2 * (PAR), a1s = 2 * (PAR) + 1;                            \
        /* ph0: MFMA(0) on afP; prefetch af(1) */                                  \
        RD_AF(afQ, 1, a0s);                                                        \
        if ((KT) + 1 < NT) stA((KT) + 1, rA10, rA11, 2 * (1 - (PAR)) + 1);         \
        __builtin_amdgcn_s_barrier();                                              \
        MFMA8(0, afP);                                                             \
        __builtin_amdgcn_s_barrier();                                              \
        /* ph1: MFMA(1) on afQ; prefetch af(2) */                                  \
        RD_AF(afP, 2, a1s);                                                        \
        if ((KT) + 2 < NT) stB((KT) + 2, 0, 2 * (PAR));                            \
        __builtin_amdgcn_s_barrier();                                              \
        MFMA8(1, afQ);                                                             \
        __builtin_amdgcn_s_barrier();                                              \
        /* ph2: MFMA(2) on afP; prefetch af(3) */                                  \
        RD_AF(afQ, 3, a1s);                                                        \
        if ((KT) + 2 < NT) stA((KT) + 2, rA00, rA01, 2 * (PAR));                   \
        __builtin_amdgcn_s_barrier();                                              \
        MFMA8(2, afP);                                                             \
        __builtin_amdgcn_s_barrier();                                              \
        /* ph3: MFMA(3) on afQ; then prefetch next tile's bf + af(0) */            \
        if ((KT) + 2 < NT) stB((KT) + 2, 1, 2 * (PAR) + 1);                        \
        if ((KT) < NT - 2) asm volatile("s_waitcnt vmcnt(6)" ::: "memory");        \
        else               asm volatile("s_waitcnt vmcnt(0)" ::: "memory");        \
        __builtin_amdgcn_s_barrier();                                              \
        MFMA8(3, afQ);                                                             \
        if (!(LAST)) {                                                             \
            RD_BF(2 * (1 - (PAR)) + (wc >> 1));                                    \
            RD_AF(afP, 0, 2 * (1 - (PAR)));                                        \
        }                                                                          \
        __builtin_amdgcn_s_barrier();                                              \
    } while (0)

    // initial fragment fill for tile 0
    RD_BF(wc >> 1);
    RD_AF(afP, 0, 0);

    for (int kt = 0; kt < NT; kt += 2) {
        TILE(kt, 0, false);
        TILE(kt + 1, 1, (kt + 1 == NT - 1));
    }

    // ---- Epilogue: acc = C^T quadrants -> packed b64 swizzled LDS stores,
    //      then fully-coalesced nontemporal 16B global stores.
#pragma unroll
    for (int mi = 0; mi < 8; mi++) {
        int row = wr * 128 + mi * 16 + lr;        // C-row (local 0..255)
#pragma unroll
        for (int ni = 0; ni < 4; ni++) {
            int col0 = wc * 64 + ni * 16 + lk * 4; // 4 consecutive C-cols
            f32x4 bia = *reinterpret_cast<const f32x4*>(bias + nb + col0);
            us4 w;
#pragma unroll
            for (int r = 0; r < 4; r++) {
                float v = acc[mi][ni][r] + bia[r];
                if (arr == 1)      v = sigmoid_f(v);
                else if (arr == 2) v = v * sigmoid_f(v);
                w[r] = f2bf(v);
            }
            int byte = (row * 512 + col0 * 2) ^ ((row & 7) << 4);
            *reinterpret_cast<us4*>(reinterpret_cast<char*>(lds) + byte) = w;
        }
    }
    __syncthreads();
#pragma unroll
    for (int it = 0; it < 16; ++it) {
        int off8 = it * 512 + tid;              // 16B-chunk id, 8192 total
        int row  = off8 >> 5;                   // 32 chunks per 256-col row
        int col8 = (off8 & 31) << 3;
        int byte = (row * 512 + col8 * 2) ^ ((row & 7) << 4);
        us8 v = *reinterpret_cast<const us8*>(reinterpret_cast<char*>(lds) + byte);
        __builtin_nontemporal_store(v,
            reinterpret_cast<us8*>(outp + (size_t)(tM + row) * D_DIM + nb + col8));
    }
#undef RD_AF
#undef RD_BF
#undef MFMA8
#undef TILE
}

// ---------------------------------------------------------------------------
// Scan pass 1: per (chunk, channel-quad): A = prod(1-d), B = local scan from 0
// ---------------------------------------------------------------------------
__global__ __launch_bounds__(256)
void scan_pass1(const unsigned short* __restrict__ dw,
                const unsigned short* __restrict__ cxw,
                float* __restrict__ Aw, float* __restrict__ Bw)
{
    int g  = blockIdx.x * 256 + threadIdx.x;
    int c  = g / (BD / 4);
    int i0 = (g % (BD / 4)) * 4;
    size_t base = (size_t)c * CLEN * BD + i0;

    float a[4]  = {1.f, 1.f, 1.f, 1.f};
    float hb[4] = {0.f, 0.f, 0.f, 0.f};
    for (int t = 0; t < CLEN; t++) {
        us4 dv = *reinterpret_cast<const us4*>(dw  + base + (size_t)t * BD);
        us4 cv = *reinterpret_cast<const us4*>(cxw + base + (size_t)t * BD);
#pragma unroll
        for (int j = 0; j < 4; j++) {
            float d = bf2f(dv[j]);
            float om = 1.f - d;
            float cand = tanh_f(bf2f(cv[j]));
            hb[j] = om * hb[j] + d * cand;
            a[j] *= om;
        }
    }
    f32x4 av = {a[0], a[1], a[2], a[3]};
    f32x4 bv = {hb[0], hb[1], hb[2], hb[3]};
    *reinterpret_cast<f32x4*>(Aw + (size_t)c * BD + i0) = av;
    *reinterpret_cast<f32x4*>(Bw + (size_t)c * BD + i0) = bv;
}

// ---------------------------------------------------------------------------
// Scan pass 2: sequential combine over chunks (tiny). Writes h[0].
// ---------------------------------------------------------------------------
__global__ __launch_bounds__(256)
void scan_pass2(const float* __restrict__ Aw, const float* __restrict__ Bw,
                const float* __restrict__ h0, float* __restrict__ hin,
                float* __restrict__ hseq)
{
    int i0 = (blockIdx.x * 256 + threadIdx.x) * 4;
    if (i0 >= BD) return;
    f32x4 h = *reinterpret_cast<const f32x4*>(h0 + i0);
    *reinterpret_cast<f32x4*>(hseq + i0) = h;
    for (int c = 0; c < CHUNKS; c++) {
        *reinterpret_cast<f32x4*>(hin + (size_t)c * BD + i0) = h;
        f32x4 A  = *reinterpret_cast<const f32x4*>(Aw + (size_t)c * BD + i0);
        f32x4 Bv = *reinterpret_cast<const f32x4*>(Bw + (size_t)c * BD + i0);
        h = A * h + Bv;
    }
}

// ---------------------------------------------------------------------------
// Scan pass 3: replay each chunk with true h_in; nt-store out and h.
// ---------------------------------------------------------------------------
__global__ __launch_bounds__(256)
void scan_pass3(const unsigned short* __restrict__ dw,
                const unsigned short* __restrict__ cxw,
                const unsigned short* __restrict__ gw,
                const float* __restrict__ hin,
                float* __restrict__ out, float* __restrict__ hseq)
{
    int g  = blockIdx.x * 256 + threadIdx.x;
    int c  = g / (BD / 4);
    int i0 = (g % (BD / 4)) * 4;
    size_t base = (size_t)c * CLEN * BD + i0;

    f32x4 h4 = *reinterpret_cast<const f32x4*>(hin + (size_t)c * BD + i0);
    float h[4] = {h4[0], h4[1], h4[2], h4[3]};
    for (int t = 0; t < CLEN; t++) {
        size_t idx = base + (size_t)t * BD;
        us4 dv = *reinterpret_cast<const us4*>(dw  + idx);
        us4 cv = *reinterpret_cast<const us4*>(cxw + idx);
        us4 gv = *reinterpret_cast<const us4*>(gw  + idx);
        f32x4 o, hv;
#pragma unroll
        for (int j = 0; j < 4; j++) {
            float d = bf2f(dv[j]);
            float om = 1.f - d;
            float cand = tanh_f(bf2f(cv[j]));
            h[j] = om * h[j] + d * cand;
            o[j] = h[j] * bf2f(gv[j]);
            hv[j] = h[j];
        }
        __builtin_nontemporal_store(o,  reinterpret_cast<f32x4*>(out + idx));
        __builtin_nontemporal_store(hv, reinterpret_cast<f32x4*>(hseq + idx + BD));
    }
}

// ---------------------------------------------------------------------------
// Fixup for channels with r_h != 0 (r_h == 0 here -> immediate exit).
// ---------------------------------------------------------------------------
__global__ __launch_bounds__(256)
void scan_fixup(const float* __restrict__ rh, const float* __restrict__ h0,
                const unsigned short* __restrict__ dw,
                const unsigned short* __restrict__ cxw,
                const unsigned short* __restrict__ gw,
                float* __restrict__ out, float* __restrict__ hseq)
{
    int i = blockIdx.x * 256 + threadIdx.x;
    if (i >= BD) return;
    float r = rh[i & (D_DIM - 1)];
    if (r == 0.0f) return;
    float h = h0[i];
    for (int t = 0; t < T_DIM; t++) {
        size_t idx = (size_t)t * BD + i;
        float d = bf2f(dw[idx]);
        float cand = tanh_f(bf2f(cxw[idx]) + r * h);
        h = (1.f - d) * h + d * cand;
        out[idx] = h * bf2f(gw[idx]);
        hseq[idx + BD] = h;
    }
}

extern "C" void kernel_launch(void* const* d_in, const int* in_sizes, int n_in,
                              void* d_out, int out_size, void* d_ws, size_t ws_size,
                              hipStream_t stream)
{
    const float* x   = (const float*)d_in[0];
    const float* h0  = (const float*)d_in[1];
    const float* Wx  = (const float*)d_in[2];
    const float* rh  = (const float*)d_in[3];
    const float* Wd  = (const float*)d_in[4];
    const float* Wg  = (const float*)d_in[5];
    const float* bx  = (const float*)d_in[6];
    const float* bdl = (const float*)d_in[7];
    const float* bg  = (const float*)d_in[8];

    float* out  = (float*)d_out;                       // [T,B,D]
    float* hseq = out + (size_t)T_DIM * BD;            // [T+1,B,D]

    unsigned short* dw  = (unsigned short*)d_ws;
    unsigned short* cxw = dw  + (size_t)M_DIM * D_DIM;
    unsigned short* gw  = cxw + (size_t)M_DIM * D_DIM;
    float* Aw  = (float*)(gw + (size_t)M_DIM * D_DIM);
    float* Bw  = Aw + (size_t)CHUNKS * BD;
    float* hin = Bw + (size_t)CHUNKS * BD;

    // bf16 x and W live in the not-yet-written `out` region (GEMM finishes
    // before scan_pass3 writes out). 67.1 MB + 6.3 MB < 134 MB.
    unsigned short* xb = (unsigned short*)d_out;
    unsigned short* Wb = xb + (size_t)M_DIM * K_DIM;

    conv_all<<<dim3((XN8 + 3 * WN8) / 256), dim3(256), 0, stream>>>(x, Wx, Wd, Wg, xb, Wb);

    gemm_fused<<<dim3((M_DIM / 256) * (N_DIM / 256)), dim3(512), 0, stream>>>(
        xb, Wb, bx, bdl, bg, cxw, dw, gw);

    scan_pass1<<<dim3(CHUNKS * BD / 4 / 256), dim3(256), 0, stream>>>(dw, cxw, Aw, Bw);
    scan_pass2<<<dim3(BD / 4 / 256 + 1), dim3(256), 0, stream>>>(Aw, Bw, h0, hin, hseq);
    scan_pass3<<<dim3(CHUNKS * BD / 4 / 256), dim3(256), 0, stream>>>(dw, cxw, gw, hin, out, hseq);
    scan_fixup<<<dim3(BD / 256), dim3(256), 0, stream>>>(rh, h0, dw, cxw, gw, out, hseq);
}